// Round 2
// baseline (171.443 us; speedup 1.0000x reference)
//
#include <hip/hip_runtime.h>

// VDP dropout:
//   keep      = (u >= 0.1f)
//   mu_out    = mu_in    * keep / 0.9
//   Sigma_out = Sigma_in * keep / 768     (D = last-dim size)
//
// Elementwise over N = B*T*D = 64*197*768 = 9,683,968 fp32 elements.
// Memory-bound: 3 reads + 2 writes per element = 20 B/elem ≈ 194 MB total.
// Roofline at 6.3 TB/s achievable: ~31 us.
//
// This revision:
//   * native clang ext_vector float4 (HIP_vector_type float4 is not a legal
//     operand for __builtin_nontemporal_store — R1 compile failure).
//   * grid-stride loop, grid capped at 2048 blocks (8 blocks/CU x 256 CU)
//     -> ~4-5 independent float4 iterations per thread for MLP/ILP.
//   * nontemporal stores for both outputs (never re-read): avoids L2/L3
//     allocation for the 77 MB output stream, keeps TCC free for inputs.
//   * loads stay cached (L3 may serve repeated bench iterations).

#define DROP_PROP 0.1f

typedef float vfloat4 __attribute__((ext_vector_type(4)));

__global__ __launch_bounds__(256) void vdp_dropout_kernel(
    const vfloat4* __restrict__ mu_in,
    const vfloat4* __restrict__ sigma_in,
    const vfloat4* __restrict__ u,
    vfloat4* __restrict__ mu_out,
    vfloat4* __restrict__ sigma_out,
    int n4)
{
    const float inv_keep = 1.0f / (1.0f - DROP_PROP);   // 1/0.9
    const float inv_d    = 1.0f / 768.0f;

    const int stride = gridDim.x * blockDim.x;

    for (int i = blockIdx.x * blockDim.x + threadIdx.x; i < n4; i += stride) {
        vfloat4 uu = u[i];
        vfloat4 m  = mu_in[i];
        vfloat4 s  = sigma_in[i];

        vfloat4 mo, so;
        #pragma unroll
        for (int j = 0; j < 4; ++j) {
            const bool keep = (uu[j] >= DROP_PROP);
            mo[j] = keep ? m[j] * inv_keep : 0.0f;
            so[j] = keep ? s[j] * inv_d    : 0.0f;
        }

        __builtin_nontemporal_store(mo, &mu_out[i]);
        __builtin_nontemporal_store(so, &sigma_out[i]);
    }
}

extern "C" void kernel_launch(void* const* d_in, const int* in_sizes, int n_in,
                              void* d_out, int out_size, void* d_ws, size_t ws_size,
                              hipStream_t stream)
{
    const float* mu_in    = (const float*)d_in[0];
    const float* sigma_in = (const float*)d_in[1];
    const float* u        = (const float*)d_in[2];

    const int n = in_sizes[0];          // 9,683,968
    float* mu_out    = (float*)d_out;           // first n elements
    float* sigma_out = (float*)d_out + n;       // next n elements

    const int n4 = n / 4;               // n % 4 == 0
    const int block = 256;
    const int max_blocks = 2048;        // 8 blocks/CU x 256 CUs
    int grid = (n4 + block - 1) / block;
    if (grid > max_blocks) grid = max_blocks;

    vdp_dropout_kernel<<<grid, block, 0, stream>>>(
        (const vfloat4*)mu_in, (const vfloat4*)sigma_in, (const vfloat4*)u,
        (vfloat4*)mu_out, (vfloat4*)sigma_out, n4);
}

// Round 4
// 170.836 us; speedup vs baseline: 1.0036x; 1.0036x over previous
//
#include <hip/hip_runtime.h>

// VDP dropout:
//   keep      = (u >= 0.1f)
//   mu_out    = mu_in    * keep / 0.9
//   Sigma_out = Sigma_in * keep / 768     (D = last-dim size)
//
// N = 64*197*768 = 9,683,968 fp32 elements. 3 reads + 2 writes = 194 MB.
// Working set (194 MB) fits the 256 MB L3 -> steady-state bench reads are
// ~50% L3-hits already (R2: FETCH 56.7 MB vs 116 MB logical).
//
// R2 counters: kernel 58 us, HBM 29% peak, VALUBusy 2.6%, VGPR_Count=12.
// Diagnosis: MLP-bound. 12 VGPRs = exactly 3 dwordx4 destinations -> only
// 3 loads in flight per wave, serialized iteration rounds.
//
// This revision (resubmitted unchanged; R3 bench never acquired a GPU):
//   * 8 floats per thread per stream (2 x dwordx4) -> 6 independent loads
//     in flight per wave (2x MLP), one-shot flat grid (no loop).
//   * plain cached stores (nt stores forced 75.6 MB of HBM write traffic
//     per dispatch; without nt the L3 absorbs the re-written output lines).

#define DROP_PROP 0.1f

typedef float vfloat4 __attribute__((ext_vector_type(4)));

__global__ __launch_bounds__(256) void vdp_dropout_kernel(
    const vfloat4* __restrict__ mu_in,
    const vfloat4* __restrict__ sigma_in,
    const vfloat4* __restrict__ u,
    vfloat4* __restrict__ mu_out,
    vfloat4* __restrict__ sigma_out,
    int n4)
{
    const float inv_keep = 1.0f / (1.0f - DROP_PROP);   // 1/0.9
    const float inv_d    = 1.0f / 768.0f;

    // Each thread handles two adjacent float4s: elements [8t, 8t+8).
    // n % 8 == 0, n4 even -> i < n4 implies i+1 < n4.
    int i = (blockIdx.x * blockDim.x + threadIdx.x) * 2;
    if (i >= n4) return;

    // Issue all 6 loads before any use: 6 independent dwordx4 in flight.
    vfloat4 u0 = u[i];
    vfloat4 u1 = u[i + 1];
    vfloat4 m0 = mu_in[i];
    vfloat4 m1 = mu_in[i + 1];
    vfloat4 s0 = sigma_in[i];
    vfloat4 s1 = sigma_in[i + 1];

    vfloat4 mo0, mo1, so0, so1;
    #pragma unroll
    for (int j = 0; j < 4; ++j) {
        const bool k0 = (u0[j] >= DROP_PROP);
        const bool k1 = (u1[j] >= DROP_PROP);
        mo0[j] = k0 ? m0[j] * inv_keep : 0.0f;
        mo1[j] = k1 ? m1[j] * inv_keep : 0.0f;
        so0[j] = k0 ? s0[j] * inv_d    : 0.0f;
        so1[j] = k1 ? s1[j] * inv_d    : 0.0f;
    }

    mu_out[i]        = mo0;
    mu_out[i + 1]    = mo1;
    sigma_out[i]     = so0;
    sigma_out[i + 1] = so1;
}

extern "C" void kernel_launch(void* const* d_in, const int* in_sizes, int n_in,
                              void* d_out, int out_size, void* d_ws, size_t ws_size,
                              hipStream_t stream)
{
    const float* mu_in    = (const float*)d_in[0];
    const float* sigma_in = (const float*)d_in[1];
    const float* u        = (const float*)d_in[2];

    const int n = in_sizes[0];          // 9,683,968
    float* mu_out    = (float*)d_out;           // first n elements
    float* sigma_out = (float*)d_out + n;       // next n elements

    const int n4 = n / 4;               // 2,420,992 (even)
    const int n8 = n4 / 2;              // 1,210,496 threads needed
    const int block = 256;
    const int grid = (n8 + block - 1) / block;  // 4729 blocks, one-shot

    vdp_dropout_kernel<<<grid, block, 0, stream>>>(
        (const vfloat4*)mu_in, (const vfloat4*)sigma_in, (const vfloat4*)u,
        (vfloat4*)mu_out, (vfloat4*)sigma_out, n4);
}